// Round 4
// baseline (606.710 us; speedup 1.0000x reference)
//
#include <hip/hip_runtime.h>
#include <hip/hip_bf16.h>

#define B_   8
#define LQ_  128
#define LK_  1024
#define H_   128

// Scratch in module BSS (d_ws size unverified). ~12.5 MB total.
__device__ float g_qp[B_ * LQ_ * H_];    // queries @ W_q
__device__ float g_kp[B_ * LK_ * H_];    // keys @ W_k
__device__ float g_sc[B_ * LQ_ * LK_];   // raw scores
__device__ float g_at[B_ * LQ_ * LK_];   // softmax(attn) weights

// Y[r,c] = sum_k X[r,k] * W[k,c].  One thread per output element.
__global__ __launch_bounds__(256) void proj_kernel(const float* __restrict__ X,
                                                   const float* __restrict__ W,
                                                   float* __restrict__ Y, int n) {
    int idx = blockIdx.x * 256 + threadIdx.x;
    if (idx >= n) return;
    int r = idx >> 7, c = idx & 127;
    float acc = 0.0f;
    for (int k = 0; k < H_; ++k) acc = fmaf(X[r * H_ + k], W[k * H_ + c], acc);
    Y[idx] = acc;
}

// scores[b,l,s] = sum_h w_v[h] * tanh(qp[b,l,h] + kp[b,s,h]).
// One block per (b,l); threads stride over s. Library tanhf (max fidelity).
__global__ __launch_bounds__(256) void score_kernel(const float* __restrict__ w_v) {
    int b = blockIdx.x >> 7, l = blockIdx.x & 127;
    __shared__ float qs[H_], wv[H_];
    int t = threadIdx.x;
    if (t < H_) {
        qs[t] = g_qp[(b * LQ_ + l) * H_ + t];
        wv[t] = w_v[t];
    }
    __syncthreads();
    for (int s = t; s < LK_; s += 256) {
        const float* kr = g_kp + (b * LK_ + s) * H_;
        float acc = 0.0f;
        for (int h = 0; h < H_; ++h) acc = fmaf(wv[h], tanhf(qs[h] + kr[h]), acc);
        g_sc[(b * LQ_ + l) * LK_ + s] = acc;
    }
}

// Reference-literal masked softmax over the full 1024 row.
// Masked entries get -1e6; expf(-1e6 - m) == 0 in f32 (same as jax/np f32/f64).
// valid==0 -> all -1e6 -> uniform, exactly like the reference.
__global__ __launch_bounds__(256) void softmax_kernel(const int* __restrict__ valid_lens) {
    __shared__ float buf[LK_];
    __shared__ float red[256];
    int b = blockIdx.x >> 7, l = blockIdx.x & 127;
    int t = threadIdx.x;
    int valid = valid_lens[b];
    valid = min(max(valid, 0), LK_);
    const float* srow = g_sc + (b * LQ_ + l) * LK_;
    float* arow = g_at + (b * LQ_ + l) * LK_;

    for (int i = t; i < LK_; i += 256) buf[i] = (i < valid) ? srow[i] : -1e6f;
    __syncthreads();

    float m = -3.0e38f;
    for (int i = t; i < LK_; i += 256) m = fmaxf(m, buf[i]);
    red[t] = m;
    __syncthreads();
    for (int s2 = 128; s2 > 0; s2 >>= 1) {
        if (t < s2) red[t] = fmaxf(red[t], red[t + s2]);
        __syncthreads();
    }
    m = red[0];
    __syncthreads();   // red is reused below

    float ps = 0.0f;
    for (int i = t; i < LK_; i += 256) {
        float e = expf(buf[i] - m);
        buf[i] = e;
        ps += e;
    }
    red[t] = ps;
    __syncthreads();
    for (int s2 = 128; s2 > 0; s2 >>= 1) {
        if (t < s2) red[t] += red[t + s2];
        __syncthreads();
    }
    float rs = 1.0f / red[0];
    for (int i = t; i < LK_; i += 256) arow[i] = buf[i] * rs;
}

// out[b,l,v] = sum_s attn[b,l,s] * values[b,s,v]. One thread per output.
__global__ __launch_bounds__(256) void pv_kernel(const float* __restrict__ values,
                                                 float* __restrict__ out) {
    int idx = blockIdx.x * 256 + threadIdx.x;   // B*LQ*H total
    int bl = idx >> 7, v = idx & 127;
    int b = bl >> 7;
    const float* a = g_at + (size_t)bl * LK_;
    float acc = 0.0f;
    for (int s = 0; s < LK_; ++s) acc = fmaf(a[s], values[(b * LK_ + s) * H_ + v], acc);
    out[idx] = acc;
}

extern "C" void kernel_launch(void* const* d_in, const int* in_sizes, int n_in,
                              void* d_out, int out_size, void* d_ws, size_t ws_size,
                              hipStream_t stream) {
    const float* queries    = (const float*)d_in[0];
    const float* keys       = (const float*)d_in[1];
    const float* values     = (const float*)d_in[2];
    const int*   valid_lens = (const int*)d_in[3];
    const float* W_q        = (const float*)d_in[4];
    const float* W_k        = (const float*)d_in[5];
    const float* w_v        = (const float*)d_in[6];
    float* out = (float*)d_out;
    (void)d_ws; (void)ws_size; (void)in_sizes; (void)n_in; (void)out_size;

    float* qp = nullptr; float* kp = nullptr;
    hipGetSymbolAddress((void**)&qp, HIP_SYMBOL(g_qp));
    hipGetSymbolAddress((void**)&kp, HIP_SYMBOL(g_kp));

    proj_kernel<<<(B_ * LQ_ * H_ + 255) / 256, 256, 0, stream>>>(queries, W_q, qp, B_ * LQ_ * H_);
    proj_kernel<<<(B_ * LK_ * H_ + 255) / 256, 256, 0, stream>>>(keys,    W_k, kp, B_ * LK_ * H_);
    score_kernel  <<<B_ * LQ_, 256, 0, stream>>>(w_v);
    softmax_kernel<<<B_ * LQ_, 256, 0, stream>>>(valid_lens);
    pv_kernel     <<<(B_ * LQ_ * H_ + 255) / 256, 256, 0, stream>>>(values, out);
}

// Round 5
// 114.253 us; speedup vs baseline: 5.3102x; 5.3102x over previous
//
#include <hip/hip_runtime.h>
#include <hip/hip_bf16.h>

#define B_   8
#define LQ_  128
#define LK_  1024
#define H_   128

// Scratch in module BSS (d_ws size unverified). ~12.5 MB total.
__device__ float g_qp[B_ * LQ_ * H_];    // queries @ W_q
__device__ float g_kp[B_ * LK_ * H_];    // keys @ W_k
__device__ float g_sc[B_ * LQ_ * LK_];   // raw scores (only [0,valid) written)
__device__ float g_at[B_ * LQ_ * LK_];   // softmax(attn) weights

// tanh(x) = 1 - 2/(exp(2x)+1); exp(2x) = exp2(x * 2/ln2).
// Overflow-safe: exp2->inf => rcp(inf)=0 => 1; exp2->0 => 1-2 = -1. ~1e-7 rel err.
__device__ __forceinline__ float fast_tanh(float x) {
    float e = __builtin_amdgcn_exp2f(x * 2.8853900817779268f);
    return fmaf(-2.0f, __builtin_amdgcn_rcpf(e + 1.0f), 1.0f);
}

// Y[r,c] = sum_k X[r,k] * W[k,c].  One thread per output element. (R3-identical)
__global__ __launch_bounds__(256) void proj_kernel(const float* __restrict__ X,
                                                   const float* __restrict__ W,
                                                   float* __restrict__ Y, int n) {
    int idx = blockIdx.x * 256 + threadIdx.x;
    if (idx >= n) return;
    int r = idx >> 7, c = idx & 127;
    float acc = 0.0f;
    for (int k = 0; k < H_; ++k) acc = fmaf(X[r * H_ + k], W[k * H_ + c], acc);
    Y[idx] = acc;
}

// scores[b,l,s] = sum_h w_v[h] * tanh(qp[b,l,h] + kp[b,s,h]),  s < valid only
// (masked s never influence the output: softmax_kernel overwrites them with -1e6
// and exp underflows to exactly 0). One block per (b,l); thread owns whole s.
// No cross-thread communication after the staging barrier -> race-free.
__global__ __launch_bounds__(256) void score_kernel(const float* __restrict__ w_v,
                                                    const int* __restrict__ valid_lens) {
    const int b = blockIdx.x >> 7, l = blockIdx.x & 127;
    __shared__ float qs[H_], wv[H_];
    const int t = threadIdx.x;
    if (t < H_) {
        qs[t] = g_qp[(b * LQ_ + l) * H_ + t];
        wv[t] = w_v[t];
    }
    __syncthreads();
    int valid = valid_lens[b];
    valid = min(max(valid, 0), LK_);
    float* srow = g_sc + (b * LQ_ + l) * LK_;
    for (int s = t; s < valid; s += 256) {
        const float4* kr = (const float4*)(g_kp + (b * LK_ + s) * H_);
        float acc = 0.0f;
        #pragma unroll 8
        for (int h4 = 0; h4 < H_ / 4; ++h4) {
            float4 k4 = kr[h4];
            const int h = h4 * 4;
            acc = fmaf(wv[h + 0], fast_tanh(qs[h + 0] + k4.x), acc);
            acc = fmaf(wv[h + 1], fast_tanh(qs[h + 1] + k4.y), acc);
            acc = fmaf(wv[h + 2], fast_tanh(qs[h + 2] + k4.z), acc);
            acc = fmaf(wv[h + 3], fast_tanh(qs[h + 3] + k4.w), acc);
        }
        srow[s] = acc;
    }
}

// Reference-literal masked softmax over the full 1024 row. (R3-identical)
__global__ __launch_bounds__(256) void softmax_kernel(const int* __restrict__ valid_lens) {
    __shared__ float buf[LK_];
    __shared__ float red[256];
    int b = blockIdx.x >> 7, l = blockIdx.x & 127;
    int t = threadIdx.x;
    int valid = valid_lens[b];
    valid = min(max(valid, 0), LK_);
    const float* srow = g_sc + (b * LQ_ + l) * LK_;
    float* arow = g_at + (b * LQ_ + l) * LK_;

    for (int i = t; i < LK_; i += 256) buf[i] = (i < valid) ? srow[i] : -1e6f;
    __syncthreads();

    float m = -3.0e38f;
    for (int i = t; i < LK_; i += 256) m = fmaxf(m, buf[i]);
    red[t] = m;
    __syncthreads();
    for (int s2 = 128; s2 > 0; s2 >>= 1) {
        if (t < s2) red[t] = fmaxf(red[t], red[t + s2]);
        __syncthreads();
    }
    m = red[0];
    __syncthreads();

    float ps = 0.0f;
    for (int i = t; i < LK_; i += 256) {
        float e = expf(buf[i] - m);
        buf[i] = e;
        ps += e;
    }
    red[t] = ps;
    __syncthreads();
    for (int s2 = 128; s2 > 0; s2 >>= 1) {
        if (t < s2) red[t] += red[t + s2];
        __syncthreads();
    }
    float rs = 1.0f / red[0];
    for (int i = t; i < LK_; i += 256) arow[i] = buf[i] * rs;
}

// out[b,l,v] = sum_s attn[b,l,s] * values[b,s,v]. One block per (b,l),
// one thread per v; attn row staged in LDS (broadcast), values coalesced.
// Weights for s >= valid are exactly 0 -> loop to valid (full row if valid==0).
__global__ __launch_bounds__(128) void pv_kernel(const float* __restrict__ values,
                                                 const int* __restrict__ valid_lens,
                                                 float* __restrict__ out) {
    __shared__ float a[LK_];
    const int b = blockIdx.x >> 7, l = blockIdx.x & 127;
    const int t = threadIdx.x;   // v index
    int valid = valid_lens[b];
    valid = min(max(valid, 0), LK_);
    const int n = (valid == 0) ? LK_ : valid;
    const float* arow = g_at + (size_t)(b * LQ_ + l) * LK_;
    for (int i = t; i < n; i += 128) a[i] = arow[i];
    __syncthreads();
    const float* vb = values + (size_t)b * LK_ * H_ + t;
    float acc = 0.0f;
    for (int s = 0; s < n; ++s) acc = fmaf(a[s], vb[s * H_], acc);
    out[(b * LQ_ + l) * H_ + t] = acc;
}

extern "C" void kernel_launch(void* const* d_in, const int* in_sizes, int n_in,
                              void* d_out, int out_size, void* d_ws, size_t ws_size,
                              hipStream_t stream) {
    const float* queries    = (const float*)d_in[0];
    const float* keys       = (const float*)d_in[1];
    const float* values     = (const float*)d_in[2];
    const int*   valid_lens = (const int*)d_in[3];
    const float* W_q        = (const float*)d_in[4];
    const float* W_k        = (const float*)d_in[5];
    const float* w_v        = (const float*)d_in[6];
    float* out = (float*)d_out;
    (void)d_ws; (void)ws_size; (void)in_sizes; (void)n_in; (void)out_size;

    float* qp = nullptr; float* kp = nullptr;
    hipGetSymbolAddress((void**)&qp, HIP_SYMBOL(g_qp));
    hipGetSymbolAddress((void**)&kp, HIP_SYMBOL(g_kp));

    proj_kernel<<<(B_ * LQ_ * H_ + 255) / 256, 256, 0, stream>>>(queries, W_q, qp, B_ * LQ_ * H_);
    proj_kernel<<<(B_ * LK_ * H_ + 255) / 256, 256, 0, stream>>>(keys,    W_k, kp, B_ * LK_ * H_);
    score_kernel  <<<B_ * LQ_, 256, 0, stream>>>(w_v, valid_lens);
    softmax_kernel<<<B_ * LQ_, 256, 0, stream>>>(valid_lens);
    pv_kernel     <<<B_ * LQ_, 128, 0, stream>>>(values, valid_lens, out);
}

// Round 6
// 99.377 us; speedup vs baseline: 6.1051x; 1.1497x over previous
//
#include <hip/hip_runtime.h>
#include <hip/hip_bf16.h>

#define B_   8
#define LQ_  128
#define LK_  1024
#define H_   128

// Scratch in module BSS (d_ws size unverified). ~12.5 MB total.
__device__ float g_qp[B_ * LQ_ * H_];    // queries @ W_q
__device__ float g_kp[B_ * LK_ * H_];    // keys @ W_k
__device__ float g_sc[B_ * LQ_ * LK_];   // raw scores (only [0,valid) written)
__device__ float g_at[B_ * LQ_ * LK_];   // softmax(attn) weights

// tanh(x) = 1 - 2/(exp(2x)+1); exp(2x) = exp2(x * 2/ln2).
// Overflow-safe: exp2->inf => rcp(inf)=0 => 1; exp2->0 => 1-2 = -1. ~1e-7 rel err.
__device__ __forceinline__ float fast_tanh(float x) {
    float e = __builtin_amdgcn_exp2f(x * 2.8853900817779268f);
    return fmaf(-2.0f, __builtin_amdgcn_rcpf(e + 1.0f), 1.0f);
}

// Y[r,c] = sum_k X[r,k] * W[k,c].  One thread per output element. (R3-identical)
__global__ __launch_bounds__(256) void proj_kernel(const float* __restrict__ X,
                                                   const float* __restrict__ W,
                                                   float* __restrict__ Y, int n) {
    int idx = blockIdx.x * 256 + threadIdx.x;
    if (idx >= n) return;
    int r = idx >> 7, c = idx & 127;
    float acc = 0.0f;
    for (int k = 0; k < H_; ++k) acc = fmaf(X[r * H_ + k], W[k * H_ + c], acc);
    Y[idx] = acc;
}

// scores[b,l,s] = sum_h w_v[h] * tanh(qp[b,l,h] + kp[b,s,h]),  s < valid only.
// grid = (B*LQ, 2): blockIdx.y halves interleave the s-range (stride 512) for
// 2x wave count (R5 showed latency slack). Writes disjoint -> race-free.
__global__ __launch_bounds__(256) void score_kernel(const float* __restrict__ w_v,
                                                    const int* __restrict__ valid_lens) {
    const int b = blockIdx.x >> 7, l = blockIdx.x & 127;
    __shared__ float qs[H_], wv[H_];
    const int t = threadIdx.x;
    if (t < H_) {
        qs[t] = g_qp[(b * LQ_ + l) * H_ + t];
        wv[t] = w_v[t];
    }
    __syncthreads();
    int valid = valid_lens[b];
    valid = min(max(valid, 0), LK_);
    float* srow = g_sc + (b * LQ_ + l) * LK_;
    for (int s = t + (blockIdx.y << 8); s < valid; s += 512) {
        const float4* kr = (const float4*)(g_kp + (b * LK_ + s) * H_);
        float acc = 0.0f;
        #pragma unroll 8
        for (int h4 = 0; h4 < H_ / 4; ++h4) {
            float4 k4 = kr[h4];
            const int h = h4 * 4;
            acc = fmaf(wv[h + 0], fast_tanh(qs[h + 0] + k4.x), acc);
            acc = fmaf(wv[h + 1], fast_tanh(qs[h + 1] + k4.y), acc);
            acc = fmaf(wv[h + 2], fast_tanh(qs[h + 2] + k4.z), acc);
            acc = fmaf(wv[h + 3], fast_tanh(qs[h + 3] + k4.w), acc);
        }
        srow[s] = acc;
    }
}

// Reference-literal masked softmax over the full 1024 row. (R3-identical)
__global__ __launch_bounds__(256) void softmax_kernel(const int* __restrict__ valid_lens) {
    __shared__ float buf[LK_];
    __shared__ float red[256];
    int b = blockIdx.x >> 7, l = blockIdx.x & 127;
    int t = threadIdx.x;
    int valid = valid_lens[b];
    valid = min(max(valid, 0), LK_);
    const float* srow = g_sc + (b * LQ_ + l) * LK_;
    float* arow = g_at + (b * LQ_ + l) * LK_;

    for (int i = t; i < LK_; i += 256) buf[i] = (i < valid) ? srow[i] : -1e6f;
    __syncthreads();

    float m = -3.0e38f;
    for (int i = t; i < LK_; i += 256) m = fmaxf(m, buf[i]);
    red[t] = m;
    __syncthreads();
    for (int s2 = 128; s2 > 0; s2 >>= 1) {
        if (t < s2) red[t] = fmaxf(red[t], red[t + s2]);
        __syncthreads();
    }
    m = red[0];
    __syncthreads();

    float ps = 0.0f;
    for (int i = t; i < LK_; i += 256) {
        float e = expf(buf[i] - m);
        buf[i] = e;
        ps += e;
    }
    red[t] = ps;
    __syncthreads();
    for (int s2 = 128; s2 > 0; s2 >>= 1) {
        if (t < s2) red[t] += red[t + s2];
        __syncthreads();
    }
    float rs = 1.0f / red[0];
    for (int i = t; i < LK_; i += 256) arow[i] = buf[i] * rs;
}

// out[b,l,v] = sum_s attn[b,l,s] * values[b,s,v]. One block per (b,l),
// 512 threads = (v in [0,128)) x (s-chunk c in [0,4), interleaved stride 4).
// Partials combined via LDS after a barrier; only c==0 writes out. Race-free.
__global__ __launch_bounds__(512) void pv_kernel(const float* __restrict__ values,
                                                 const int* __restrict__ valid_lens,
                                                 float* __restrict__ out) {
    __shared__ float a[LK_];
    __shared__ float part[4][128];
    const int b = blockIdx.x >> 7, l = blockIdx.x & 127;
    const int t = threadIdx.x;
    const int v = t & 127;
    const int c = t >> 7;            // s-chunk 0..3; uniform per wave
    int valid = valid_lens[b];
    valid = min(max(valid, 0), LK_);
    const int n = (valid == 0) ? LK_ : valid;   // softmax row is uniform if valid==0
    const float* arow = g_at + (size_t)(b * LQ_ + l) * LK_;
    for (int i = t; i < n; i += 512) a[i] = arow[i];
    __syncthreads();
    const float* vb = values + (size_t)b * LK_ * H_ + v;
    float acc = 0.0f;
    #pragma unroll 4
    for (int s = c; s < n; s += 4) acc = fmaf(a[s], vb[(size_t)s * H_], acc);
    part[c][v] = acc;
    __syncthreads();
    if (c == 0) {
        acc += part[1][v] + part[2][v] + part[3][v];
        out[(b * LQ_ + l) * H_ + v] = acc;
    }
}

extern "C" void kernel_launch(void* const* d_in, const int* in_sizes, int n_in,
                              void* d_out, int out_size, void* d_ws, size_t ws_size,
                              hipStream_t stream) {
    const float* queries    = (const float*)d_in[0];
    const float* keys       = (const float*)d_in[1];
    const float* values     = (const float*)d_in[2];
    const int*   valid_lens = (const int*)d_in[3];
    const float* W_q        = (const float*)d_in[4];
    const float* W_k        = (const float*)d_in[5];
    const float* w_v        = (const float*)d_in[6];
    float* out = (float*)d_out;
    (void)d_ws; (void)ws_size; (void)in_sizes; (void)n_in; (void)out_size;

    float* qp = nullptr; float* kp = nullptr;
    hipGetSymbolAddress((void**)&qp, HIP_SYMBOL(g_qp));
    hipGetSymbolAddress((void**)&kp, HIP_SYMBOL(g_kp));

    proj_kernel<<<(B_ * LQ_ * H_ + 255) / 256, 256, 0, stream>>>(queries, W_q, qp, B_ * LQ_ * H_);
    proj_kernel<<<(B_ * LK_ * H_ + 255) / 256, 256, 0, stream>>>(keys,    W_k, kp, B_ * LK_ * H_);
    score_kernel  <<<dim3(B_ * LQ_, 2), 256, 0, stream>>>(w_v, valid_lens);
    softmax_kernel<<<B_ * LQ_, 256, 0, stream>>>(valid_lens);
    pv_kernel     <<<B_ * LQ_, 512, 0, stream>>>(values, valid_lens, out);
}

// Round 7
// 86.678 us; speedup vs baseline: 6.9996x; 1.1465x over previous
//
#include <hip/hip_runtime.h>
#include <hip/hip_bf16.h>

#define B_   8
#define LQ_  128
#define LK_  1024
#define H_   128

// Projection outputs in module BSS (~4.7 MB).
__device__ float g_qp[B_ * LQ_ * H_];    // queries @ W_q
__device__ float g_kp[B_ * LK_ * H_];    // keys @ W_k

// tanh(x) = 1 - 2/(exp(2x)+1); exp(2x) = exp2(x * 2/ln2).
// Overflow-safe: exp2->inf => rcp(inf)=0 => 1; exp2->0 => 1-2 = -1. ~1e-7 rel err.
__device__ __forceinline__ float fast_tanh(float x) {
    float e = __builtin_amdgcn_exp2f(x * 2.8853900817779268f);
    return fmaf(-2.0f, __builtin_amdgcn_rcpf(e + 1.0f), 1.0f);
}

// Both projections in one launch. Blocks [0,512): q (131072 elems = exactly 512
// blocks, so every block is branch-uniform); blocks [512,...): k.
// One thread per output element, math byte-identical to the green R3 proj.
__global__ __launch_bounds__(256) void proj_kernel(const float* __restrict__ q,
                                                   const float* __restrict__ k,
                                                   const float* __restrict__ Wq,
                                                   const float* __restrict__ Wk) {
    int idx = blockIdx.x * 256 + threadIdx.x;
    const int NQ = B_ * LQ_ * H_;
    const float* X; const float* W; float* Y;
    if (idx < NQ) { X = q; W = Wq; Y = g_qp; }
    else          { X = k; W = Wk; Y = g_kp; idx -= NQ; }
    const int r = idx >> 7, c = idx & 127;
    float acc = 0.0f;
    for (int kk = 0; kk < H_; ++kk) acc = fmaf(X[r * H_ + kk], W[kk * H_ + c], acc);
    Y[idx] = acc;
}

// Fused scores + masked softmax + PV. One block per (b,l), 512 threads.
// Phase 1: sc[s] = sum_h w_v[h]*tanh(q[h]+k[s,h]) for s < valid (LDS).
// Phase 2: block-tree softmax over sc[0..n) (uniform branch on valid==0).
// Phase 3: out[v] = rinv * sum_s sc[s]*values[b,s,v], 4-way s-split via LDS.
// All cross-thread communication is LDS + __syncthreads -> race-free.
__global__ __launch_bounds__(512) void fused_attn(const float* __restrict__ values,
                                                  const int* __restrict__ valid_lens,
                                                  const float* __restrict__ w_v,
                                                  float* __restrict__ out) {
    __shared__ float sc[LK_];
    __shared__ float qs[H_], wv[H_];
    __shared__ float red[512];
    __shared__ float part[4][H_];
    const int t = threadIdx.x;
    const int b = blockIdx.x >> 7, l = blockIdx.x & 127;
    int valid = valid_lens[b];
    valid = min(max(valid, 0), LK_);

    if (t < H_) {
        qs[t] = g_qp[(b * LQ_ + l) * H_ + t];
        wv[t] = w_v[t];
    }
    __syncthreads();

    // Phase 1: scores (masked s never computed; their softmax weight is 0).
    for (int s = t; s < valid; s += 512) {
        const float4* kr = (const float4*)(g_kp + (b * LK_ + s) * H_);
        float acc = 0.0f;
        #pragma unroll 8
        for (int h4 = 0; h4 < H_ / 4; ++h4) {
            float4 k4 = kr[h4];
            const int h = h4 * 4;
            acc = fmaf(wv[h + 0], fast_tanh(qs[h + 0] + k4.x), acc);
            acc = fmaf(wv[h + 1], fast_tanh(qs[h + 1] + k4.y), acc);
            acc = fmaf(wv[h + 2], fast_tanh(qs[h + 2] + k4.z), acc);
            acc = fmaf(wv[h + 3], fast_tanh(qs[h + 3] + k4.w), acc);
        }
        sc[s] = acc;
    }
    __syncthreads();

    // Phase 2: softmax weights in sc, normalization deferred to epilogue.
    int n;
    float rinv;
    if (valid == 0) {                 // all -1e6 in ref -> uniform
        n = LK_;
        for (int i = t; i < LK_; i += 512) sc[i] = 1.0f;
        rinv = 1.0f / 1024.0f;
        __syncthreads();
    } else {
        n = valid;
        float m = -3.0e38f;
        for (int i = t; i < n; i += 512) m = fmaxf(m, sc[i]);
        red[t] = m;
        __syncthreads();
        for (int s2 = 256; s2 > 0; s2 >>= 1) {
            if (t < s2) red[t] = fmaxf(red[t], red[t + s2]);
            __syncthreads();
        }
        m = red[0];
        __syncthreads();              // red reused
        float ps = 0.0f;
        for (int i = t; i < n; i += 512) {
            float e = __builtin_amdgcn_exp2f((sc[i] - m) * 1.44269504f);
            sc[i] = e;
            ps += e;
        }
        red[t] = ps;
        __syncthreads();
        for (int s2 = 256; s2 > 0; s2 >>= 1) {
            if (t < s2) red[t] += red[t + s2];
            __syncthreads();
        }
        rinv = 1.0f / red[0];
    }

    // Phase 3: PV. v = t&127, s-chunk c = t>>7 (stride-4 interleave).
    const int v = t & 127;
    const int c = t >> 7;
    const float* vb = values + (size_t)b * LK_ * H_ + v;
    float acc = 0.0f;
    #pragma unroll 4
    for (int s = c; s < n; s += 4) acc = fmaf(sc[s], vb[(size_t)s * H_], acc);
    part[c][v] = acc;
    __syncthreads();
    if (c == 0) {
        acc += part[1][v] + part[2][v] + part[3][v];
        out[(b * LQ_ + l) * H_ + v] = acc * rinv;
    }
}

extern "C" void kernel_launch(void* const* d_in, const int* in_sizes, int n_in,
                              void* d_out, int out_size, void* d_ws, size_t ws_size,
                              hipStream_t stream) {
    const float* queries    = (const float*)d_in[0];
    const float* keys       = (const float*)d_in[1];
    const float* values     = (const float*)d_in[2];
    const int*   valid_lens = (const int*)d_in[3];
    const float* W_q        = (const float*)d_in[4];
    const float* W_k        = (const float*)d_in[5];
    const float* w_v        = (const float*)d_in[6];
    float* out = (float*)d_out;
    (void)d_ws; (void)ws_size; (void)in_sizes; (void)n_in; (void)out_size;

    const int NPROJ = B_ * LQ_ * H_ + B_ * LK_ * H_;   // 1179648 = 4608 blocks
    proj_kernel<<<NPROJ / 256, 256, 0, stream>>>(queries, keys, W_q, W_k);
    fused_attn <<<B_ * LQ_, 512, 0, stream>>>(values, valid_lens, w_v, out);
}

// Round 8
// 50.615 us; speedup vs baseline: 11.9868x; 1.7125x over previous
//
#include <hip/hip_runtime.h>
#include <hip/hip_bf16.h>

#define B_   8
#define LQ_  128
#define LK_  1024
#define H_   128

// Projection outputs in module BSS (~4.7 MB).
__device__ float g_qp[B_ * LQ_ * H_];    // queries @ W_q
__device__ float g_kp[B_ * LK_ * H_];    // keys @ W_k

// tanh(x) = 1 - 2/(exp(2x)+1); exp(2x) = exp2(x * 2/ln2).
// Overflow-safe: exp2->inf => rcp(inf)=0 => 1; exp2->0 => 1-2 = -1. ~1e-7 rel err.
__device__ __forceinline__ float fast_tanh(float x) {
    float e = __builtin_amdgcn_exp2f(x * 2.8853900817779268f);
    return fmaf(-2.0f, __builtin_amdgcn_rcpf(e + 1.0f), 1.0f);
}

// Tiled projection, W fully LDS-resident (64KB), X tile 32x128 (16KB).
// Grid: 288 blocks = 32 q-row-tiles + 256 k-row-tiles (branch block-uniform).
// Thread (r4 = t>>5, c4 = t&31) computes a 4x4 output tile from LDS only.
// k-accumulation order identical to the green naive proj (k = 0..127).
__global__ __launch_bounds__(256) void proj_kernel(const float* __restrict__ q,
                                                   const float* __restrict__ k,
                                                   const float* __restrict__ Wq,
                                                   const float* __restrict__ Wk,
                                                   float* __restrict__ outq_unused) {
    __shared__ float Ws[H_ * H_];        // 64 KB
    __shared__ float Xs[32 * H_];        // 16 KB
    const int t = threadIdx.x;
    const int tile = blockIdx.x;
    const float* X; const float* W; float* Y; int r0;
    if (tile < 32) { X = q; W = Wq; Y = g_qp; r0 = tile * 32; }
    else           { X = k; W = Wk; Y = g_kp; r0 = (tile - 32) * 32; }

    // stage W: 16384 floats = 4096 float4, 16/thread, coalesced
    #pragma unroll
    for (int u = 0; u < 16; ++u) {
        int idx = u * 256 + t;
        *(float4*)(Ws + idx * 4) = *(const float4*)(W + idx * 4);
    }
    // stage X tile: 4096 floats = 1024 float4, 4/thread
    #pragma unroll
    for (int u = 0; u < 4; ++u) {
        int idx = u * 256 + t;
        int r = idx >> 5, c = idx & 31;
        *(float4*)(Xs + r * H_ + c * 4) = *(const float4*)(X + (r0 + r) * H_ + c * 4);
    }
    __syncthreads();

    const int r4 = t >> 5;               // [0,8)
    const int c4 = t & 31;               // [0,32)
    float acc[4][4] = {};
    #pragma unroll 4
    for (int kk = 0; kk < H_; ++kk) {
        float4 w4 = *(const float4*)(Ws + kk * H_ + c4 * 4);
        #pragma unroll
        for (int i = 0; i < 4; ++i) {
            float x = Xs[(r4 * 4 + i) * H_ + kk];
            acc[i][0] = fmaf(x, w4.x, acc[i][0]);
            acc[i][1] = fmaf(x, w4.y, acc[i][1]);
            acc[i][2] = fmaf(x, w4.z, acc[i][2]);
            acc[i][3] = fmaf(x, w4.w, acc[i][3]);
        }
    }
    #pragma unroll
    for (int i = 0; i < 4; ++i) {
        float4 o = {acc[i][0], acc[i][1], acc[i][2], acc[i][3]};
        *(float4*)(Y + (r0 + r4 * 4 + i) * H_ + c4 * 4) = o;
    }
}

// Fused scores + masked softmax + PV; 2 q-rows per block.
// Grid 512 = (b = blk>>6, l0 = (blk&63)*2), 512 threads.
// Phase 1: thread owns s; loads k-row once, feeds both l's.   (disjoint sc writes)
// Phase 2: 256 threads per row: strided local + shfl64 + LDS combine of 4 waves.
// Phase 3: thread (c=t>>7, v=t&127): values loaded once -> acc[2]; partials in LDS.
// All cross-thread traffic via LDS with __syncthreads; branches block-uniform.
__global__ __launch_bounds__(512, 2) void fused_attn(const float* __restrict__ values,
                                                     const int* __restrict__ valid_lens,
                                                     const float* __restrict__ w_v,
                                                     float* __restrict__ out) {
    __shared__ float qs[2][H_];
    __shared__ float wv[H_];
    __shared__ float sc[2][LK_];
    __shared__ float red[16];
    __shared__ float rinvs[2];
    __shared__ float part[4][2][H_];
    const int t = threadIdx.x;
    const int b = blockIdx.x >> 6, l0 = (blockIdx.x & 63) * 2;
    int valid = valid_lens[b];
    valid = min(max(valid, 0), LK_);

    if (t < 256) qs[t >> 7][t & 127] = g_qp[(b * LQ_ + l0 + (t >> 7)) * H_ + (t & 127)];
    else if (t < 384) wv[t - 256] = w_v[t - 256];
    __syncthreads();

    // ---- Phase 1: scores for s < valid (masked s have softmax weight 0) ----
    for (int s = t; s < valid; s += 512) {
        const float4* kr = (const float4*)(g_kp + (b * LK_ + s) * H_);
        float a0 = 0.0f, a1 = 0.0f;
        #pragma unroll 4
        for (int h4 = 0; h4 < H_ / 4; ++h4) {
            float4 k4 = kr[h4];
            float4 w4 = *(const float4*)(wv + h4 * 4);
            float4 q0 = *(const float4*)(qs[0] + h4 * 4);
            float4 q1 = *(const float4*)(qs[1] + h4 * 4);
            a0 = fmaf(w4.x, fast_tanh(q0.x + k4.x), a0);
            a1 = fmaf(w4.x, fast_tanh(q1.x + k4.x), a1);
            a0 = fmaf(w4.y, fast_tanh(q0.y + k4.y), a0);
            a1 = fmaf(w4.y, fast_tanh(q1.y + k4.y), a1);
            a0 = fmaf(w4.z, fast_tanh(q0.z + k4.z), a0);
            a1 = fmaf(w4.z, fast_tanh(q1.z + k4.z), a1);
            a0 = fmaf(w4.w, fast_tanh(q0.w + k4.w), a0);
            a1 = fmaf(w4.w, fast_tanh(q1.w + k4.w), a1);
        }
        sc[0][s] = a0;
        sc[1][s] = a1;
    }
    __syncthreads();

    // ---- Phase 2: softmax weights in sc (unnormalized), 1/sum in rinvs ----
    int n;
    if (valid == 0) {                    // ref: all -1e6 -> uniform
        n = LK_;
        for (int i = t; i < LK_; i += 512) { sc[0][i] = 1.0f; sc[1][i] = 1.0f; }
        if (t == 0) { rinvs[0] = 1.0f / 1024.0f; rinvs[1] = 1.0f / 1024.0f; }
    } else {
        n = valid;
        const int r = t >> 8, tt = t & 255;      // 256 threads per row
        const int w4id = tt >> 6;                // wave-quarter within row
        float* srow = sc[r];
        float m = -3.0e38f;
        for (int i = tt; i < n; i += 256) m = fmaxf(m, srow[i]);
        #pragma unroll
        for (int kk = 32; kk; kk >>= 1) m = fmaxf(m, __shfl_xor(m, kk, 64));
        if ((tt & 63) == 0) red[r * 4 + w4id] = m;
        __syncthreads();
        m = fmaxf(fmaxf(red[r * 4], red[r * 4 + 1]), fmaxf(red[r * 4 + 2], red[r * 4 + 3]));
        float ps = 0.0f;
        for (int i = tt; i < n; i += 256) {
            float e = __builtin_amdgcn_exp2f((srow[i] - m) * 1.44269504f);
            srow[i] = e;
            ps += e;
        }
        #pragma unroll
        for (int kk = 32; kk; kk >>= 1) ps += __shfl_xor(ps, kk, 64);
        if ((tt & 63) == 0) red[8 + r * 4 + w4id] = ps;
        __syncthreads();
        if (t < 2) {
            float s4 = red[8 + t * 4] + red[8 + t * 4 + 1] + red[8 + t * 4 + 2] + red[8 + t * 4 + 3];
            rinvs[t] = 1.0f / s4;
        }
    }
    __syncthreads();

    // ---- Phase 3: PV. values loaded once, feeds both l's ----
    const int c = t >> 7;                // s-chunk [0,4)
    const int v = t & 127;
    const float* vb = values + (size_t)b * LK_ * H_ + v;
    float ac0 = 0.0f, ac1 = 0.0f;
    #pragma unroll 8
    for (int s = c; s < n; s += 4) {
        float vv = vb[(size_t)s * H_];
        ac0 = fmaf(sc[0][s], vv, ac0);
        ac1 = fmaf(sc[1][s], vv, ac1);
    }
    part[c][0][v] = ac0;
    part[c][1][v] = ac1;
    __syncthreads();
    if (t < 256) {
        const int l = t >> 7, vv = t & 127;
        float o = (part[0][l][vv] + part[1][l][vv]) + (part[2][l][vv] + part[3][l][vv]);
        out[(b * LQ_ + l0 + l) * H_ + vv] = o * rinvs[l];
    }
}

extern "C" void kernel_launch(void* const* d_in, const int* in_sizes, int n_in,
                              void* d_out, int out_size, void* d_ws, size_t ws_size,
                              hipStream_t stream) {
    const float* queries    = (const float*)d_in[0];
    const float* keys       = (const float*)d_in[1];
    const float* values     = (const float*)d_in[2];
    const int*   valid_lens = (const int*)d_in[3];
    const float* W_q        = (const float*)d_in[4];
    const float* W_k        = (const float*)d_in[5];
    const float* w_v        = (const float*)d_in[6];
    float* out = (float*)d_out;
    (void)d_ws; (void)ws_size; (void)in_sizes; (void)n_in; (void)out_size;

    proj_kernel<<<288, 256, 0, stream>>>(queries, keys, W_q, W_k, nullptr);
    fused_attn <<<512, 512, 0, stream>>>(values, valid_lens, w_v, out);
}

// Round 9
// 46.123 us; speedup vs baseline: 13.1543x; 1.0974x over previous
//
#include <hip/hip_runtime.h>
#include <hip/hip_bf16.h>

#define B_   8
#define LQ_  128
#define LK_  1024
#define H_   128

// exp(2*proj) in module BSS (~4.7 MB). tanh(q+k) = 1 - 2/(EQ*EK + 1),
// so the score kernel needs ONLY these, not the raw projections.
__device__ float g_eq[B_ * LQ_ * H_];    // exp(2 * (queries @ W_q))
__device__ float g_ek[B_ * LK_ * H_];    // exp(2 * (keys    @ W_k))

#define C2LOG2E 2.8853900817779268f      // 2/ln(2): exp(2x) = exp2(x * C2LOG2E)

// Tiled projection, W fully LDS-resident (64KB), X tile 32x128 (16KB).
// Grid: 288 blocks = 32 q-row-tiles + 256 k-row-tiles (branch block-uniform).
// Epilogue writes exp(2*acc) — overflow-safe (q_proj ~ N(0,1); f32 inf only
// past x~44, and inf/0 still give correct tanh downstream via rcp).
__global__ __launch_bounds__(256) void proj_kernel(const float* __restrict__ q,
                                                   const float* __restrict__ k,
                                                   const float* __restrict__ Wq,
                                                   const float* __restrict__ Wk) {
    __shared__ float Ws[H_ * H_];        // 64 KB
    __shared__ float Xs[32 * H_];        // 16 KB
    const int t = threadIdx.x;
    const int tile = blockIdx.x;
    const float* X; const float* W; float* Y; int r0;
    if (tile < 32) { X = q; W = Wq; Y = g_eq; r0 = tile * 32; }
    else           { X = k; W = Wk; Y = g_ek; r0 = (tile - 32) * 32; }

    #pragma unroll
    for (int u = 0; u < 16; ++u) {
        int idx = u * 256 + t;
        *(float4*)(Ws + idx * 4) = *(const float4*)(W + idx * 4);
    }
    #pragma unroll
    for (int u = 0; u < 4; ++u) {
        int idx = u * 256 + t;
        int r = idx >> 5, c = idx & 31;
        *(float4*)(Xs + r * H_ + c * 4) = *(const float4*)(X + (r0 + r) * H_ + c * 4);
    }
    __syncthreads();

    const int r4 = t >> 5;               // [0,8)
    const int c4 = t & 31;               // [0,32)
    float acc[4][4] = {};
    #pragma unroll 4
    for (int kk = 0; kk < H_; ++kk) {
        float4 w4 = *(const float4*)(Ws + kk * H_ + c4 * 4);
        #pragma unroll
        for (int i = 0; i < 4; ++i) {
            float x = Xs[(r4 * 4 + i) * H_ + kk];
            acc[i][0] = fmaf(x, w4.x, acc[i][0]);
            acc[i][1] = fmaf(x, w4.y, acc[i][1]);
            acc[i][2] = fmaf(x, w4.z, acc[i][2]);
            acc[i][3] = fmaf(x, w4.w, acc[i][3]);
        }
    }
    #pragma unroll
    for (int i = 0; i < 4; ++i) {
        float4 o;
        o.x = __builtin_amdgcn_exp2f(acc[i][0] * C2LOG2E);
        o.y = __builtin_amdgcn_exp2f(acc[i][1] * C2LOG2E);
        o.z = __builtin_amdgcn_exp2f(acc[i][2] * C2LOG2E);
        o.w = __builtin_amdgcn_exp2f(acc[i][3] * C2LOG2E);
        *(float4*)(Y + (r0 + r4 * 4 + i) * H_ + c4 * 4) = o;
    }
}

// Fused scores + masked softmax + PV; 2 q-rows per block. (R8 structure; phase 1
// strength-reduced: score = Wsum - 2 * sum_h w_h * rcp(EQ_h*EK_h + 1).)
__global__ __launch_bounds__(512, 2) void fused_attn(const float* __restrict__ values,
                                                     const int* __restrict__ valid_lens,
                                                     const float* __restrict__ w_v,
                                                     float* __restrict__ out) {
    __shared__ float qs[2][H_];          // EQ for the 2 rows
    __shared__ float wv[H_];
    __shared__ float sc[2][LK_];
    __shared__ float red[16];
    __shared__ float rinvs[2];
    __shared__ float wsum_s;
    __shared__ float part[4][2][H_];
    const int t = threadIdx.x;
    const int b = blockIdx.x >> 6, l0 = (blockIdx.x & 63) * 2;
    int valid = valid_lens[b];
    valid = min(max(valid, 0), LK_);

    if (t < 256) qs[t >> 7][t & 127] = g_eq[(b * LQ_ + l0 + (t >> 7)) * H_ + (t & 127)];
    else if (t < 384) wv[t - 256] = w_v[t - 256];
    __syncthreads();
    if (t == 0) {                        // Wsum = sum_h w_v[h] (block-scalar)
        float s = 0.0f;
        for (int h = 0; h < H_; ++h) s += wv[h];
        wsum_s = s;
    }
    __syncthreads();
    const float wsum = wsum_s;

    // ---- Phase 1: scores for s < valid (masked s have softmax weight 0) ----
    for (int s = t; s < valid; s += 512) {
        const float4* kr = (const float4*)(g_ek + (b * LK_ + s) * H_);
        float a0 = 0.0f, a1 = 0.0f;
        #pragma unroll 8
        for (int h4 = 0; h4 < H_ / 4; ++h4) {
            float4 e4 = kr[h4];
            float4 w4 = *(const float4*)(wv + h4 * 4);
            float4 q0 = *(const float4*)(qs[0] + h4 * 4);
            float4 q1 = *(const float4*)(qs[1] + h4 * 4);
            a0 = fmaf(w4.x, __builtin_amdgcn_rcpf(fmaf(q0.x, e4.x, 1.0f)), a0);
            a1 = fmaf(w4.x, __builtin_amdgcn_rcpf(fmaf(q1.x, e4.x, 1.0f)), a1);
            a0 = fmaf(w4.y, __builtin_amdgcn_rcpf(fmaf(q0.y, e4.y, 1.0f)), a0);
            a1 = fmaf(w4.y, __builtin_amdgcn_rcpf(fmaf(q1.y, e4.y, 1.0f)), a1);
            a0 = fmaf(w4.z, __builtin_amdgcn_rcpf(fmaf(q0.z, e4.z, 1.0f)), a0);
            a1 = fmaf(w4.z, __builtin_amdgcn_rcpf(fmaf(q1.z, e4.z, 1.0f)), a1);
            a0 = fmaf(w4.w, __builtin_amdgcn_rcpf(fmaf(q0.w, e4.w, 1.0f)), a0);
            a1 = fmaf(w4.w, __builtin_amdgcn_rcpf(fmaf(q1.w, e4.w, 1.0f)), a1);
        }
        sc[0][s] = fmaf(-2.0f, a0, wsum);
        sc[1][s] = fmaf(-2.0f, a1, wsum);
    }
    __syncthreads();

    // ---- Phase 2: softmax weights in sc (unnormalized), 1/sum in rinvs ----
    int n;
    if (valid == 0) {                    // ref: all -1e6 -> uniform
        n = LK_;
        for (int i = t; i < LK_; i += 512) { sc[0][i] = 1.0f; sc[1][i] = 1.0f; }
        if (t == 0) { rinvs[0] = 1.0f / 1024.0f; rinvs[1] = 1.0f / 1024.0f; }
    } else {
        n = valid;
        const int r = t >> 8, tt = t & 255;      // 256 threads per row
        const int w4id = tt >> 6;
        float* srow = sc[r];
        float m = -3.0e38f;
        for (int i = tt; i < n; i += 256) m = fmaxf(m, srow[i]);
        #pragma unroll
        for (int kk = 32; kk; kk >>= 1) m = fmaxf(m, __shfl_xor(m, kk, 64));
        if ((tt & 63) == 0) red[r * 4 + w4id] = m;
        __syncthreads();
        m = fmaxf(fmaxf(red[r * 4], red[r * 4 + 1]), fmaxf(red[r * 4 + 2], red[r * 4 + 3]));
        float ps = 0.0f;
        for (int i = tt; i < n; i += 256) {
            float e = __builtin_amdgcn_exp2f((srow[i] - m) * 1.44269504f);
            srow[i] = e;
            ps += e;
        }
        #pragma unroll
        for (int kk = 32; kk; kk >>= 1) ps += __shfl_xor(ps, kk, 64);
        if ((tt & 63) == 0) red[8 + r * 4 + w4id] = ps;
        __syncthreads();
        if (t < 2) {
            float s4 = red[8 + t * 4] + red[8 + t * 4 + 1] + red[8 + t * 4 + 2] + red[8 + t * 4 + 3];
            rinvs[t] = 1.0f / s4;
        }
    }
    __syncthreads();

    // ---- Phase 3: PV. values loaded once, feeds both l's ----
    const int c = t >> 7;                // s-chunk [0,4)
    const int v = t & 127;
    const float* vb = values + (size_t)b * LK_ * H_ + v;
    float ac0 = 0.0f, ac1 = 0.0f;
    #pragma unroll 8
    for (int s = c; s < n; s += 4) {
        float vv = vb[(size_t)s * H_];
        ac0 = fmaf(sc[0][s], vv, ac0);
        ac1 = fmaf(sc[1][s], vv, ac1);
    }
    part[c][0][v] = ac0;
    part[c][1][v] = ac1;
    __syncthreads();
    if (t < 256) {
        const int l = t >> 7, vv = t & 127;
        float o = (part[0][l][vv] + part[1][l][vv]) + (part[2][l][vv] + part[3][l][vv]);
        out[(b * LQ_ + l0 + l) * H_ + vv] = o * rinvs[l];
    }
}

extern "C" void kernel_launch(void* const* d_in, const int* in_sizes, int n_in,
                              void* d_out, int out_size, void* d_ws, size_t ws_size,
                              hipStream_t stream) {
    const float* queries    = (const float*)d_in[0];
    const float* keys       = (const float*)d_in[1];
    const float* values     = (const float*)d_in[2];
    const int*   valid_lens = (const int*)d_in[3];
    const float* W_q        = (const float*)d_in[4];
    const float* W_k        = (const float*)d_in[5];
    const float* w_v        = (const float*)d_in[6];
    float* out = (float*)d_out;
    (void)d_ws; (void)ws_size; (void)in_sizes; (void)n_in; (void)out_size;

    proj_kernel<<<288, 256, 0, stream>>>(queries, keys, W_q, W_k);
    fused_attn <<<512, 512, 0, stream>>>(values, valid_lens, w_v, out);
}